// Round 1
// 298.140 us; speedup vs baseline: 1.0776x; 1.0776x over previous
//
#include <hip/hip_runtime.h>
#include <hip/hip_bf16.h>

// LoraConv: B=32,E=5,CIN=COUT=256,K=3,H=W=56,R=4, scaling=4
#define BB    32
#define EE    5
#define HH    56
#define WW    56
#define KKC   2304
#define SCAL  4.0f

typedef __attribute__((ext_vector_type(8))) short short8;
typedef __attribute__((ext_vector_type(4))) float f32x4;

// Wf2:   [E][9 tap][8 cic][256 co][32 ci] bf16
// xpad2: [B][8 cic][58 row][58 col][32 ci] bf16, zero halo.
//        Within each col's 64B group, 16B granule q stored at q ^ ((col>>1)&3).
#define WF2_PER_E  (9 * 8 * 256 * 32)     // 589824
#define XP2_PER_BC (58 * 58 * 32)         // 107648 per (b,cic)

#define NXPB (58 * BB)                    // 1856 xpose blocks
#define NPRB (256 * EE)                   // 1280 prep blocks

__device__ __forceinline__ void gload_lds16(const void* g, void* l) {
    __builtin_amdgcn_global_load_lds(
        (const __attribute__((address_space(1))) unsigned int*)g,
        (__attribute__((address_space(3))) unsigned int*)l, 16, 0, 0);
}

__device__ __forceinline__ unsigned short f2bf(float f) {   // RNE, finite inputs
    unsigned int u = __float_as_uint(f);
    return (unsigned short)((u + 0x7FFFu + ((u >> 16) & 1u)) >> 16);
}

// ---------------------------------------------------------------------------
// Kernel 1 (fused): blockIdx.x < NXPB  -> xpose block (rp, b)
//                   blockIdx.x >= NXPB -> prep block (co, e)
// prep and xpose are independent; fusing removes one graph node and lets the
// cheap prep blocks fill the xpose tail.
// ---------------------------------------------------------------------------
__global__ __launch_bounds__(256) void lora_prep_xpose_kernel(
    const float* __restrict__ x,        // [32,256,56,56]
    const float* __restrict__ weight,   // [256,256,3,3]
    const float* __restrict__ lora_A,   // [E,12,768]
    const float* __restrict__ lora_B,   // [E,768,12]
    unsigned short* __restrict__ Wf2,
    unsigned short* __restrict__ xpad2)
{
    __shared__ union ShU {
        struct { float As[12 * 768]; float Bs[3][12]; } p;   // 37 KB (prep)
        float xt[56][33];                                    // 7.4 KB (xpose)
    } sh;
    const int tid = threadIdx.x;

    if (blockIdx.x >= NXPB) {
        // ---------------- prep: Wf2[e][tap][cic][co][ci32] ----------------
        const int pid = blockIdx.x - NXPB;
        const int co  = pid & 255;
        const int e   = pid >> 8;
        const int ci  = tid;

        for (int i = tid; i < 12 * 768; i += 256)
            sh.p.As[i] = lora_A[e * 12 * 768 + i];
        if (tid < 36)
            sh.p.Bs[tid / 12][tid % 12] =
                lora_B[((size_t)e * 768 + co * 3 + tid / 12) * 12 + tid % 12];
        __syncthreads();

        const float* wrow = weight + (size_t)co * KKC + ci * 9;
        const int cic = ci >> 5, ci32 = ci & 31;
        #pragma unroll
        for (int tap = 0; tap < 9; ++tap) {
            int idx  = ci * 9 + tap;
            int q    = idx / 768;
            int i768 = idx - q * 768;
            float acc = 0.f;
            #pragma unroll
            for (int r = 0; r < 12; ++r)
                acc += sh.p.Bs[q][r] * sh.p.As[r * 768 + i768];
            float v = wrow[tap] + SCAL * acc;
            Wf2[((size_t)((e * 9 + tap) * 8 + cic)) * 8192 + co * 32 + ci32] = f2bf(v);
        }
        return;
    }

    // ---------------- xpose: x fp32 -> xpad2 bf16 swizzled ----------------
    const int bid = blockIdx.x;
    const int b   = bid / 58;
    const int rp  = bid - b * 58;
    unsigned short* xp = xpad2 + (size_t)b * 8 * XP2_PER_BC;
    const uint4 z4 = {0u, 0u, 0u, 0u};

    if (rp == 0 || rp == 57) {          // full halo row for all 8 cic planes
        for (int t = tid; t < 1856; t += 256) {
            int cic = t / 232, q = t % 232;
            ((uint4*)(xp + ((size_t)cic * 3364 + rp * 58) * 32))[q] = z4;
        }
        return;
    }
    if (tid < 64) {                      // column halos cp=0, cp=57
        int cic = tid >> 3, which = (tid >> 2) & 1, q = tid & 3;
        ((uint4*)(xp + ((size_t)cic * 3364 + rp * 58 + (which ? 57 : 0)) * 32))[q] = z4;
    }

    const int row = rp - 1;
    const float* xb = x + (size_t)b * 256 * 3136 + row * 56;

    for (int cic = 0; cic < 8; ++cic) {
        __syncthreads();
        #pragma unroll
        for (int it = 0; it < 7; ++it) {     // 32 ch x 56 cols, coalesced fp32
            int t = it * 256 + tid;
            int i = t / 56, c = t - i * 56;
            sh.xt[c][i] = xb[(size_t)(cic * 32 + i) * 3136 + c];  // stride 33: no conflict
        }
        __syncthreads();
        if (tid < 224) {                     // c = tid>>2, logical quad = tid&3
            int c  = tid >> 2, gq = tid & 3;
            int cp = c + 1;
            int gphys = gq ^ ((cp >> 1) & 3);
            unsigned int w[4];
            #pragma unroll
            for (int j = 0; j < 4; ++j) {    // reads <=2-way aliased: free
                unsigned short lo = f2bf(sh.xt[c][gq * 8 + 2 * j + 0]);
                unsigned short hi = f2bf(sh.xt[c][gq * 8 + 2 * j + 1]);
                w[j] = (unsigned int)lo | ((unsigned int)hi << 16);
            }
            uint4 pk; pk.x = w[0]; pk.y = w[1]; pk.z = w[2]; pk.w = w[3];
            *(uint4*)(xp + ((size_t)cic * 3364 + rp * 58 + cp) * 32 + gphys * 8) = pk;
        }
    }
}

// ---------------------------------------------------------------------------
// Kernel 2: conv. Block = 128 co x 224 pos (4 rows). ci-chunk outer (LDS X,
// double-buffered, 1 barrier/chunk), tap inner (9x reuse).
// W global->VGPR with TWO-tap-ahead prefetch (covers ~200cy L2 latency; the
// stream crosses chunk boundaries). pgk offsets packed 2-per-reg to keep the
// wave under the 256 unified-VGPR / 2-waves-per-SIMD budget.
// Swizzled LDS: granule(row,col,q) at (row*58+col)*4 + (q ^ ((col>>1)&3)).
// ---------------------------------------------------------------------------
__global__ __launch_bounds__(256, 2) void lora_conv_mfma_kernel(
    const unsigned short* __restrict__ xpad2,
    const unsigned short* __restrict__ Wf2,
    const float* __restrict__ scores,
    float* __restrict__ out)
{
    const int y0   = blockIdx.x * 4;     // output rows y0..y0+3
    const int co0  = blockIdx.y * 128;
    const int b    = blockIdx.z;
    const int tid  = threadIdx.x;
    const int wave = tid >> 6;
    const int lane = tid & 63;
    const int ln15 = lane & 15;
    const int quad = lane >> 4;
    const int wm2  = (wave & 1) * 64;    // co sub-tile
    const int wn2  = (wave >> 1) * 112;  // pos sub-tile

    __shared__ short8 Xlds[2][1392];     // 2 x (6 rows x 58 cols x 4 granules)
    __shared__ int sExp;

    if (tid == 0) {
        const float* s = scores + b * EE;
        int best = 0; float bv = s[0];
        #pragma unroll
        for (int j = 1; j < EE; ++j) { float v = s[j]; if (v > bv) { bv = v; best = j; } }
        sExp = best;
    }

    const unsigned short* xsrc0 = xpad2 + (size_t)b * 8 * XP2_PER_BC + y0 * 58 * 32;

    // stage ci-chunk `cic` into buffer `buf` (22272 B contiguous)
    auto stage = [&](int cic, int buf) {
        const unsigned short* src = xsrc0 + (size_t)cic * XP2_PER_BC;
        char* dst = (char*)&Xlds[buf][0];
        #pragma unroll
        for (int i = 0; i < 5; ++i) {
            int G = i * 256 + tid;
            gload_lds16(src + (size_t)G * 8, dst + (size_t)G * 16);
        }
        if (tid < 112) {
            int G = 1280 + tid;
            gload_lds16(src + (size_t)G * 8, dst + (size_t)G * 16);
        }
    };

    stage(0, 0);
    __syncthreads();
    const int e = sExp;

    // W fragment base: row = co0+wm2+ln15 (+tm*16), k-offset quad*8 (+cic*32)
    const unsigned short* Wb =
        Wf2 + (size_t)e * WF2_PER_E + (co0 + wm2 + ln15) * 32 + quad * 8;
    // strides (shorts): tm -> 512, tap -> 65536, cic -> 8192

    // B-fragment byte offsets per (tn, k2), packed: k2 0/1 in pg01 lo/hi, k2=2 in pg2
    int pg01[7], pg2[7];
    #pragma unroll
    for (int tn = 0; tn < 7; ++tn) {
        int pos = wn2 + tn * 16 + ln15;
        int r = pos / 56, c = pos - r * 56;
        int o[3];
        #pragma unroll
        for (int k2 = 0; k2 < 3; ++k2) {
            int cc = c + k2;
            int g  = quad ^ ((cc >> 1) & 3);
            o[k2] = (r * 232 + cc * 4 + g) * 16;      // < 2^15
        }
        pg01[tn] = o[0] | (o[1] << 16);
        pg2[tn]  = o[2];
    }

    f32x4 acc[4][7];
    #pragma unroll
    for (int tm = 0; tm < 4; ++tm)
        #pragma unroll
        for (int tn = 0; tn < 7; ++tn)
            acc[tm][tn] = (f32x4){0.f, 0.f, 0.f, 0.f};

    short8 A0[4], A1[4], A2[4];
    #pragma unroll
    for (int tm = 0; tm < 4; ++tm) {                 // prologue: taps 0,1 of chunk 0
        A0[tm] = *(const short8*)(Wb + 0 * 65536 + tm * 512);
        A1[tm] = *(const short8*)(Wb + 1 * 65536 + tm * 512);
    }

    for (int cic = 0; cic < 8; ++cic) {
        const unsigned short* Wc = Wb + cic * 8192;
        const char* Xb = (const char*)&Xlds[cic & 1][0];
        #pragma unroll
        for (int tap = 0; tap < 9; ++tap) {
            if (tap == 0 && cic < 7) stage(cic + 1, (cic & 1) ^ 1);
            // prefetch W for stream position +2 (wraps into next chunk)
            if (tap < 7) {
                #pragma unroll
                for (int tm = 0; tm < 4; ++tm)
                    A2[tm] = *(const short8*)(Wc + (tap + 2) * 65536 + tm * 512);
            } else if (cic < 7) {
                #pragma unroll
                for (int tm = 0; tm < 4; ++tm)
                    A2[tm] = *(const short8*)(Wc + 8192 + (tap - 7) * 65536 + tm * 512);
            }
            const int k1 = tap / 3, k2 = tap % 3;
            __builtin_amdgcn_s_setprio(1);
            #pragma unroll
            for (int tn = 0; tn < 7; ++tn) {
                int off = (k2 == 0) ? (pg01[tn] & 0xffff)
                        : (k2 == 1) ? (pg01[tn] >> 16)
                                    : pg2[tn];
                short8 bfr = *(const short8*)(Xb + off + k1 * 3712);
                #pragma unroll
                for (int tm = 0; tm < 4; ++tm)
                    acc[tm][tn] = __builtin_amdgcn_mfma_f32_16x16x32_bf16(
                        A0[tm], bfr, acc[tm][tn], 0, 0, 0);
            }
            __builtin_amdgcn_s_setprio(0);
            #pragma unroll
            for (int tm = 0; tm < 4; ++tm) { A0[tm] = A1[tm]; A1[tm] = A2[tm]; }
        }
        if (cic < 7) __syncthreads();   // staging landed + old-buf reads done
    }

    // epilogue: D row m = quad*4+reg (+tm*16), col n = ln15 (+tn*16)
    #pragma unroll
    for (int tm = 0; tm < 4; ++tm) {
        #pragma unroll
        for (int tn = 0; tn < 7; ++tn) {
            int n = wn2 + tn * 16 + ln15;
            int r = n / 56, c = n - r * 56;
            #pragma unroll
            for (int reg = 0; reg < 4; ++reg) {
                int m = co0 + wm2 + tm * 16 + quad * 4 + reg;
                out[(((size_t)b * 256 + m) * HH + y0 + r) * WW + c] = acc[tm][tn][reg];
            }
        }
    }
}

// ---------------------------------------------------------------------------
extern "C" void kernel_launch(void* const* d_in, const int* in_sizes, int n_in,
                              void* d_out, int out_size, void* d_ws, size_t ws_size,
                              hipStream_t stream) {
    const float* x      = (const float*)d_in[0];
    const float* scores = (const float*)d_in[1];
    const float* weight = (const float*)d_in[2];
    const float* lora_A = (const float*)d_in[3];
    const float* lora_B = (const float*)d_in[4];
    float* out = (float*)d_out;

    // workspace: Wf2 bf16 (5.9MB) | xpad2 bf16 (55.1MB)
    char* ws = (char*)d_ws;
    unsigned short* Wf2   = (unsigned short*)(ws + 256);
    unsigned short* xpad2 = (unsigned short*)(ws + 256 + (size_t)EE * WF2_PER_E * 2);

    lora_prep_xpose_kernel<<<dim3(NXPB + NPRB), 256, 0, stream>>>(
        x, weight, lora_A, lora_B, Wf2, xpad2);
    lora_conv_mfma_kernel<<<dim3(14, 2, BB), 256, 0, stream>>>(xpad2, Wf2, scores, out);
}